// Round 7
// baseline (748.411 us; speedup 1.0000x reference)
//
#include <hip/hip_runtime.h>

#define TEMP 0.07f
#define NSLOT 64   // 32 row-side (seg index) + 32 col-side (macro R)

typedef __attribute__((ext_vector_type(4))) float f32x4;
typedef __attribute__((ext_vector_type(4))) int   i32x4;
typedef __attribute__((ext_vector_type(8))) int   i32x8;

// L2-normalize rows of X (fp32, N x 512) -> fp8 e4m3 (1 B/elem). One wave/row.
// Also zeroes the scalar output (replaces a hipMemsetAsync dispatch).
__global__ __launch_bounds__(256) void knorm(const float* __restrict__ X,
                                             unsigned char* __restrict__ Fq,
                                             float* __restrict__ out, int D) {
  if (blockIdx.x == 0 && threadIdx.x == 0) *out = 0.f;
  int row = blockIdx.x * 4 + (threadIdx.x >> 6);
  int lane = threadIdx.x & 63;
  const float4* xr = (const float4*)(X + (size_t)row * D);
  float4 a = xr[lane];
  float4 b = xr[lane + 64];
  float ss = a.x*a.x + a.y*a.y + a.z*a.z + a.w*a.w
           + b.x*b.x + b.y*b.y + b.z*b.z + b.w*b.w;
  #pragma unroll
  for (int off = 1; off < 64; off <<= 1) ss += __shfl_xor(ss, off, 64);
  float r = rsqrtf(ss);
  int lo = 0, hi = 0;
  lo = __builtin_amdgcn_cvt_pk_fp8_f32(a.x*r, a.y*r, lo, false);
  lo = __builtin_amdgcn_cvt_pk_fp8_f32(a.z*r, a.w*r, lo, true);
  hi = __builtin_amdgcn_cvt_pk_fp8_f32(b.x*r, b.y*r, hi, false);
  hi = __builtin_amdgcn_cvt_pk_fp8_f32(b.z*r, b.w*r, hi, true);
  unsigned char* op = Fq + (size_t)row * D;
  *(int*)(op + lane * 4)       = lo;
  *(int*)(op + 256 + lane * 4) = hi;
}

// Symmetric SupCon GEMM, 8-wave BM=256 blocks, exact-residency grid.
// Macro-rows R in [0,32) (256 rows = row-tiles 2R,2R+1); col walk j in
// [2R, 63]. 2-tile segments (s) except R<16 where the last two merge into
// one 4-tile block: 496 + 16 = 512 blocks == 2/CU residency, no tail.
// Per block: A (256 rows x 512 B) in registers across 8 waves (wave w owns
// rows rowbase+32w); B half-tiles (64 rows x 512 B) double-buffered in
// 2x32KB LDS, counted vmcnt(4) + raw-barrier pipeline (R2-proven).
// Diagonal bookkeeping (seg s==0): tile j=2R -> waves>=4 dead (below-diag
// sub-tile), no col-side; tile j=2R+1 -> col-side from waves<4 only.
// Col partials: per tile, quad-reduce -> cred[2][8][128] -> finish read
// rides the NEXT step's data barrier (lgkmcnt(0) fence before it).
// Slots: row-side = s (0..31), col-side = 32+R; one writer per (slot,row);
// s==0 blocks zero-fill the never-written slots for their 256 rows.
__global__ __launch_bounds__(512, 4)
void kmain(const unsigned char* __restrict__ F, const int* __restrict__ tgt,
           float* __restrict__ psum, float* __restrict__ pmask, int N, int D) {
  __shared__ __align__(16) unsigned char Bs[2][64 * 512];  // 2 x 32 KB dbuf
  __shared__ float cred[2][8][128];                        // 8 KB col reduce
  __shared__ int tgts[512];

  const int tid  = threadIdx.x;
  const int lane = tid & 63;
  const int wave = tid >> 6;          // 0..7
  const int quad = lane >> 4;
  const int l15  = lane & 15;

  // ---- decode block -> (R, s, nt) ----
  int R, s, nt;
  {
    int b = (int)blockIdx.x;
    if (b < 16) { R = b; s = 30 - R; nt = 4; }      // 4-tile blocks first
    else {
      int c = b - 16; R = 0;
      for (;;) { int cnt = (R < 16) ? (30 - R) : (32 - R);
                 if (c < cnt) break; c -= cnt; ++R; }
      s = c; nt = 2;
    }
  }
  const int  j0      = 2 * R + 2 * s;
  const int  lim     = 2 * nt;
  const int  rowbase = R << 8;
  const bool dseg    = (s == 0);
  const int  segsR   = (R < 16) ? (31 - R) : (32 - R);  // blocks (row-slots) of R

  // ---- zero-fill duty (s==0 blocks): unwritten (slot,row) pairs ----
  if (dseg) {
    float* P = (tid & 256) ? pmask : psum;
    const int r2 = tid & 255;
    for (int sl = segsR; sl < 32; ++sl)
      P[(size_t)sl * N + rowbase + r2] = 0.f;
    for (int sl = 32 + R + (r2 >> 7); sl < 64; ++sl)
      P[(size_t)sl * N + rowbase + r2] = 0.f;
  }

  // ---- A fragments: wave w -> rows rowbase+32w .. +31 ----
  i32x8 af[2][4];
  #pragma unroll
  for (int mi = 0; mi < 2; ++mi) {
    const unsigned char* rp = F + (size_t)(rowbase + wave*32 + mi*16 + l15) * 512 + quad*32;
    #pragma unroll
    for (int ks = 0; ks < 4; ++ks) {
      i32x4 lo = *(const i32x4*)(rp + ks*128);
      i32x4 hi = *(const i32x4*)(rp + ks*128 + 16);
      af[mi][ks] = __builtin_shufflevector(lo, hi, 0,1,2,3,4,5,6,7);
    }
  }

  int trow[2][4];
  #pragma unroll
  for (int mi = 0; mi < 2; ++mi)
    #pragma unroll
    for (int r = 0; r < 4; ++r)
      trow[mi][r] = tgt[rowbase + wave*32 + mi*16 + quad*4 + r];

  for (int i = tid; i < nt * 128; i += 512) tgts[i] = tgt[j0 * 128 + i];

  float se[2][4], ms[2][4];
  #pragma unroll
  for (int mi = 0; mi < 2; ++mi)
    #pragma unroll
    for (int r = 0; r < 4; ++r) { se[mi][r] = 0.f; ms[mi][r] = 0.f; }
  f32x4 ce[2], cm[2];   // per-CURRENT-tile col accumulators [half][ni]

  const float C1 = (1.0f / TEMP) * 1.4426950408889634f;
  const float C0 = -C1;
  const int sw0 = (quad * 2) ^ (l15 & 7);   // read-side swizzle (row&7 == l15&7)

  // stage half-step p (tile j0+(p>>1), half p&1): 64 rows x 512 B = 32 KB.
  // 2048 16B slots over 512 threads -> 4 loads/lane; phys slot ^= (row&7).
  auto STAGE = [&](int p) {
    const int rbase = (j0 + (p >> 1)) * 128 + (p & 1) * 64;
    unsigned char* db = &Bs[0][0] + (p & 1) * 32768;
    #pragma unroll
    for (int it = 0; it < 4; ++it) {
      const int L   = it * 512 + tid;
      const int row = L >> 5;
      const int ks  = (L & 31) ^ (row & 7);
      const unsigned char* gp = F + (size_t)(rbase + row) * 512 + ks * 16;
      __builtin_amdgcn_global_load_lds(
          (const __attribute__((address_space(1))) void*)gp,
          (__attribute__((address_space(3))) void*)(db + L * 16), 16, 0, 0);
    }
  };

  __syncthreads();            // retire A/trow/tgts/zero-fill; tgts visible
  STAGE(0);                   // 4 loads/lane in flight

  int pend = -1;              // col-tile jc whose cred awaits the finish read
  #pragma unroll
  for (int p = 0; p < 8; ++p) {
    if (p < lim) {            // block-uniform
      if (p + 1 < lim) {
        STAGE(p + 1);         // <=8/lane in flight
        asm volatile("s_waitcnt vmcnt(4)" ::: "memory");   // step p landed
      } else {
        asm volatile("s_waitcnt vmcnt(0)" ::: "memory");
      }
      __builtin_amdgcn_s_barrier();           // data p ready (cred too)

      if (pend >= 0) {                        // finish previous tile's col side
        if (tid < 256) {
          const int col = tid & 127, arr = tid >> 7;
          float v = 0.f;
          #pragma unroll
          for (int w = 0; w < 8; ++w) v += cred[arr][w][col];
          (arr ? pmask : psum)[(size_t)(32 + R) * N + pend * 128 + col] = v;
        }
        pend = -1;
      }

      const int c = p >> 1, h = p & 1;
      const int jc = j0 + c;
      if (h == 0) { ce[0] = (f32x4){0,0,0,0}; ce[1] = (f32x4){0,0,0,0};
                    cm[0] = (f32x4){0,0,0,0}; cm[1] = (f32x4){0,0,0,0}; }

      // ---- COMP: 32 MFMA per wave on its own A rows ----
      f32x4 acc[2][4];
      #pragma unroll
      for (int mi = 0; mi < 2; ++mi)
        #pragma unroll
        for (int ni = 0; ni < 4; ++ni)
          acc[mi][ni] = (f32x4){0.f, 0.f, 0.f, 0.f};

      const unsigned char* bb  = &Bs[0][0] + (p & 1) * 32768 + l15 * 512;
      const unsigned char* bp0 = bb + sw0 * 16;
      const unsigned char* bp1 = bb + (sw0 ^ 1) * 16;

      #pragma unroll
      for (int ks = 0; ks < 4; ++ks) {
        #pragma unroll
        for (int ni = 0; ni < 4; ++ni) {
          i32x4 b0 = *(const i32x4*)(bp0 + ni*8192 + ks*128);
          i32x4 b1 = *(const i32x4*)(bp1 + ni*8192 + ks*128);
          i32x8 bv = __builtin_shufflevector(b0, b1, 0,1,2,3,4,5,6,7);
          acc[0][ni] = __builtin_amdgcn_mfma_scale_f32_16x16x128_f8f6f4(
              af[0][ks], bv, acc[0][ni], 0, 0, 0, 0x7F7F7F7F, 0, 0x7F7F7F7F);
          acc[1][ni] = __builtin_amdgcn_mfma_scale_f32_16x16x128_f8f6f4(
              af[1][ks], bv, acc[1][ni], 0, 0, 0, 0x7F7F7F7F, 0, 0x7F7F7F7F);
        }
      }

      // wave-uniform liveness: dead = below-diag sub-tile (r1, 2R)
      const bool liveRow = !(dseg && c == 0 && wave >= 4);
      const bool liveCol = (!dseg) || (c >= 2) || (c == 1 && wave < 4);

      int tcg[4];
      #pragma unroll
      for (int ni = 0; ni < 4; ++ni) tcg[ni] = tgts[c*128 + h*64 + ni*16 + l15];
      #pragma unroll
      for (int mi = 0; mi < 2; ++mi)
        #pragma unroll
        for (int ni = 0; ni < 4; ++ni)
          #pragma unroll
          for (int r = 0; r < 4; ++r) {
            float v = acc[mi][ni][r];
            float e = __builtin_amdgcn_exp2f(fmaf(v, C1, C0));
            bool mt = (tcg[ni] == trow[mi][r]);
            if (liveRow) { se[mi][r] += e; if (mt) ms[mi][r] += v; }
            if (liveCol) { ce[h][ni] += e; if (mt) cm[h][ni] += v; }
          }
      __builtin_amdgcn_s_barrier();           // buf p reads done

      if (h == 1) {                           // tile c complete: emit cred
        const bool anycol = !(dseg && c == 0);
        if (anycol) {
          #pragma unroll
          for (int g = 0; g < 2; ++g)
            #pragma unroll
            for (int ni = 0; ni < 4; ++ni) {
              float e = ce[g][ni], m = cm[g][ni];
              e += __shfl_xor(e, 16, 64); e += __shfl_xor(e, 32, 64);
              m += __shfl_xor(m, 16, 64); m += __shfl_xor(m, 32, 64);
              if (quad == 0) {
                cred[0][wave][g*64 + ni*16 + l15] = e;
                cred[1][wave][g*64 + ni*16 + l15] = m;
              }
            }
          asm volatile("s_waitcnt lgkmcnt(0)" ::: "memory");  // cred in LDS pre-barrier
          pend = jc;
        }
      }
    }
  }

  // ---- final pending col tile (always set: last tile has col side) ----
  if (pend >= 0) {
    __builtin_amdgcn_s_barrier();
    if (tid < 256) {
      const int col = tid & 127, arr = tid >> 7;
      float v = 0.f;
      #pragma unroll
      for (int w = 0; w < 8; ++w) v += cred[arr][w][col];
      (arr ? pmask : psum)[(size_t)(32 + R) * N + pend * 128 + col] = v;
    }
  }

  // ---- row-side partials -> slot s ----
  #pragma unroll
  for (int mi = 0; mi < 2; ++mi)
    #pragma unroll
    for (int r = 0; r < 4; ++r) {
      float sv = se[mi][r], mv = ms[mi][r];
      #pragma unroll
      for (int off = 1; off < 16; off <<= 1) {
        sv += __shfl_xor(sv, off, 64);
        mv += __shfl_xor(mv, off, 64);
      }
      if (l15 == 0) {
        int row = rowbase + wave*32 + mi*16 + quad*4 + r;
        psum [(size_t)s * N + row] = sv;
        pmask[(size_t)s * N + row] = mv;
      }
    }
}

// finalize: 32 blocks x 256 rows; per-block histogram, per-row term,
// wave reduce, one atomicAdd per block into pre-zeroed out.
__global__ __launch_bounds__(256) void kfinal(
    const float* __restrict__ psum, const float* __restrict__ pmask,
    const int* __restrict__ tgt, float* __restrict__ out, int N, int nslot) {
  __shared__ int h[128];
  __shared__ float wsum[4];
  const int tid = threadIdx.x;
  if (tid < 128) h[tid] = 0;
  __syncthreads();
  for (int i = tid; i < N; i += 256) atomicAdd(&h[tgt[i] & 127], 1);
  __syncthreads();

  const int i = blockIdx.x * 256 + tid;
  float s = 0.f, m = 0.f;
  #pragma unroll 8
  for (int sp = 0; sp < nslot; ++sp) {
    s += psum[(size_t)sp * N + i];
    m += pmask[(size_t)sp * N + i];
  }
  const float invT = 1.0f / TEMP;
  float cnt = (float)(h[tgt[i] & 127] - 1);
  float term = (m - 1.0f) * invT / cnt - (logf(s) + invT);
  #pragma unroll
  for (int off = 1; off < 64; off <<= 1) term += __shfl_xor(term, off, 64);
  if ((tid & 63) == 0) wsum[tid >> 6] = term;
  __syncthreads();
  if (tid == 0)
    atomicAdd(out, -(wsum[0] + wsum[1] + wsum[2] + wsum[3]) / (float)N);
}

extern "C" void kernel_launch(void* const* d_in, const int* in_sizes, int n_in,
                              void* d_out, int out_size, void* d_ws, size_t ws_size,
                              hipStream_t stream) {
  const float* X  = (const float*)d_in[0];
  const int* tgt  = (const int*)d_in[1];
  float* out      = (float*)d_out;
  const int N = in_sizes[1];
  const int D = in_sizes[0] / N;

  char* w = (char*)d_ws;
  unsigned char* Fq = (unsigned char*)w;
  size_t off = (size_t)N * D;                           // fp8: 1 B/elem (4 MB)
  float* psum  = (float*)(w + off);
  size_t psz = (size_t)NSLOT * N * sizeof(float);       // 2 MB
  off += psz;
  float* pmask = (float*)(w + off);                     // total ws ~8 MB

  knorm<<<N / 4, 256, 0, stream>>>(X, Fq, out, D);
  kmain<<<512, 512, 0, stream>>>(Fq, tgt, psum, pmask, N, D);
  kfinal<<<N / 256, 256, 0, stream>>>(psum, pmask, tgt, out, N, NSLOT);
}

// Round 8
// 241.530 us; speedup vs baseline: 3.0986x; 3.0986x over previous
//
#include <hip/hip_runtime.h>

#define TEMP 0.07f
#define NSLOT 35   // 4 row-side (q) + 31 col-side (slot 3+t, t=1..31)

typedef __attribute__((ext_vector_type(4))) float f32x4;
typedef __attribute__((ext_vector_type(4))) int   i32x4;
typedef __attribute__((ext_vector_type(8))) int   i32x8;

// L2-normalize rows of X (fp32, N x 512) -> fp8 e4m3 (1 B/elem). One wave/row.
// Also zeroes the scalar output (replaces a hipMemsetAsync dispatch).
__global__ __launch_bounds__(256) void knorm(const float* __restrict__ X,
                                             unsigned char* __restrict__ Fq,
                                             float* __restrict__ out, int D) {
  if (blockIdx.x == 0 && threadIdx.x == 0) *out = 0.f;
  int row = blockIdx.x * 4 + (threadIdx.x >> 6);
  int lane = threadIdx.x & 63;
  const float4* xr = (const float4*)(X + (size_t)row * D);
  float4 a = xr[lane];
  float4 b = xr[lane + 64];
  float ss = a.x*a.x + a.y*a.y + a.z*a.z + a.w*a.w
           + b.x*b.x + b.y*b.y + b.z*b.z + b.w*b.w;
  #pragma unroll
  for (int off = 1; off < 64; off <<= 1) ss += __shfl_xor(ss, off, 64);
  float r = rsqrtf(ss);
  int lo = 0, hi = 0;
  lo = __builtin_amdgcn_cvt_pk_fp8_f32(a.x*r, a.y*r, lo, false);
  lo = __builtin_amdgcn_cvt_pk_fp8_f32(a.z*r, a.w*r, lo, true);
  hi = __builtin_amdgcn_cvt_pk_fp8_f32(b.x*r, b.y*r, hi, false);
  hi = __builtin_amdgcn_cvt_pk_fp8_f32(b.z*r, b.w*r, hi, true);
  unsigned char* op = Fq + (size_t)row * D;
  *(int*)(op + lane * 4)       = lo;
  *(int*)(op + 256 + lane * 4) = hi;
}

// Symmetric SupCon GEMM, t-walk enumeration, depth-2 triple-buffer pipeline.
// Block (I,q) [b = q*64+I, 256 blocks]: A = rows of tile I (registers,
// 4 waves x 32 rows); walks tiles J=(I+t)%64, t = 8q+1..8q+8 (16 half-steps
// of 64 cols). Every unordered pair once: t=1..31 row+col sides; t=32
// (q==3,c==7) computed by both partner blocks, row-side only. Diagonal
// (t=0) excluded from GEMM, added analytically in kfinal (more accurate:
// reference sim_ii = 1/T exactly).
// Pipeline: 3 x 32 KB LDS stage buffers (96 KB -> 1 block/CU; 4 waves own
// the full VGPR budget -> no spill), depth-2 prefetch, counted vmcnt(8),
// ONE raw barrier/step (triple-buffer makes the write target provably
// drained at the top-of-step barrier: STAGE(p+2) writes buf (p-1)%3, all
// waves finished reading it at step p-1 before this barrier).
// Col partials: per tile, quad-reduce -> cred (quad0), lgkm fence; finish
// (4-wave sum + global write) rides the NEXT even step's barrier.
// Slots: row-side q (0..3); col-side 3+t (4..34). Every (slot,row) written
// by exactly one block; all slots fully covered -> no memset.
__global__ __launch_bounds__(256, 1)
void kmain(const unsigned char* __restrict__ F, const int* __restrict__ tgt,
           float* __restrict__ psum, float* __restrict__ pmask, int N, int D) {
  __shared__ __align__(16) unsigned char Bs[3][64 * 512];  // 96 KB
  __shared__ float cred[2][4][128];
  __shared__ int tgts[1024];

  const int tid  = threadIdx.x;
  const int lane = tid & 63;
  const int wave = tid >> 6;          // 0..3
  const int quad = lane >> 4;
  const int l15  = lane & 15;

  const int I  = blockIdx.x & 63;
  const int q  = blockIdx.x >> 6;     // 0..3
  const int t0 = q * 8;
  const int rowbase = I * 128;

  // ---- A fragments: 2 mi x 4 ksteps x 32 fp8 ----
  i32x8 af[2][4];
  #pragma unroll
  for (int mi = 0; mi < 2; ++mi) {
    const unsigned char* rp = F + (size_t)(rowbase + wave*32 + mi*16 + l15) * 512 + quad*32;
    #pragma unroll
    for (int ks = 0; ks < 4; ++ks) {
      i32x4 lo = *(const i32x4*)(rp + ks*128);
      i32x4 hi = *(const i32x4*)(rp + ks*128 + 16);
      af[mi][ks] = __builtin_shufflevector(lo, hi, 0,1,2,3,4,5,6,7);
    }
  }

  int trow[2][4];
  #pragma unroll
  for (int mi = 0; mi < 2; ++mi)
    #pragma unroll
    for (int r = 0; r < 4; ++r)
      trow[mi][r] = tgt[rowbase + wave*32 + mi*16 + quad*4 + r];

  // col targets for the 8 tiles (wraps mod 64)
  #pragma unroll
  for (int it = 0; it < 4; ++it) {
    int i = tid + it * 256;
    int tile = (I + t0 + 1 + (i >> 7)) & 63;
    tgts[i] = tgt[tile * 128 + (i & 127)];
  }

  float se[2][4], ms[2][4];
  #pragma unroll
  for (int mi = 0; mi < 2; ++mi)
    #pragma unroll
    for (int r = 0; r < 4; ++r) { se[mi][r] = 0.f; ms[mi][r] = 0.f; }
  f32x4 ce[2], cm[2];   // current-tile col accumulators [half]

  const float C1 = (1.0f / TEMP) * 1.4426950408889634f;
  const float C0 = -C1;
  const int sw0 = (quad * 2) ^ (l15 & 7);   // read-side swizzle (row&7 == l15&7)

  // stage half-step s: tile (I+t0+1+(s>>1))%64, half s&1 -> Bs[s%3].
  // 2048 16B slots / 256 threads = 8 loads; phys slot p holds logical p^(row&7).
  auto STAGE = [&](int s) {
    const int tile  = (I + t0 + 1 + (s >> 1)) & 63;
    const int rbase = tile * 128 + (s & 1) * 64;
    unsigned char* db = &Bs[0][0] + (s % 3) * 32768;
    #pragma unroll
    for (int it = 0; it < 8; ++it) {
      const int L   = it * 256 + tid;
      const int row = L >> 5;
      const int ks  = (L & 31) ^ (row & 7);
      const unsigned char* gp = F + (size_t)(rbase + row) * 512 + ks * 16;
      __builtin_amdgcn_global_load_lds(
          (const __attribute__((address_space(1))) void*)gp,
          (__attribute__((address_space(3))) void*)(db + L * 16), 16, 0, 0);
    }
  };

  __syncthreads();            // retire A/trow/tgts; clean vmcnt slate
  STAGE(0);
  STAGE(1);                   // 16 loads in flight (depth 2)

  #pragma unroll
  for (int p = 0; p < 16; ++p) {
    if (p < 15) asm volatile("s_waitcnt vmcnt(8)" ::: "memory");  // stage p landed
    else        asm volatile("s_waitcnt vmcnt(0)" ::: "memory");
    __builtin_amdgcn_s_barrier();   // all waves: done reading buf (p-1)%3; cred(p-2) visible

    if (p + 2 < 16) STAGE(p + 2);   // writes buf (p+2)%3 == (p-1)%3 (drained)

    // finish col side of tile cf=(p-2)/2 (cred written at end of step p-1)
    if (p >= 2 && (p & 1) == 0) {
      const int cf = (p - 2) >> 1;        // 0..6 (always has col side)
      const int tf = t0 + 1 + cf;
      const int Jf = (I + tf) & 63;
      const int col = tid & 127, arr = tid >> 7;
      float v = cred[arr][0][col] + cred[arr][1][col]
              + cred[arr][2][col] + cred[arr][3][col];
      (arr ? pmask : psum)[(size_t)(3 + tf) * N + Jf * 128 + col] = v;
    }

    const int c = p >> 1, h = p & 1;
    const bool lc = !(q == 3 && c == 7);   // t=32: no col side (block-uniform)
    if (h == 0) {
      ce[0] = (f32x4){0,0,0,0}; ce[1] = (f32x4){0,0,0,0};
      cm[0] = (f32x4){0,0,0,0}; cm[1] = (f32x4){0,0,0,0};
    }

    // ---- COMP on Bs[p%3] ----
    f32x4 acc[2][4];
    #pragma unroll
    for (int mi = 0; mi < 2; ++mi)
      #pragma unroll
      for (int ni = 0; ni < 4; ++ni)
        acc[mi][ni] = (f32x4){0.f, 0.f, 0.f, 0.f};

    const unsigned char* bb  = &Bs[0][0] + (p % 3) * 32768 + l15 * 512;
    const unsigned char* bp0 = bb + sw0 * 16;
    const unsigned char* bp1 = bb + (sw0 ^ 1) * 16;

    #pragma unroll
    for (int ks = 0; ks < 4; ++ks) {
      #pragma unroll
      for (int ni = 0; ni < 4; ++ni) {
        i32x4 b0 = *(const i32x4*)(bp0 + ni*8192 + ks*128);
        i32x4 b1 = *(const i32x4*)(bp1 + ni*8192 + ks*128);
        i32x8 bv = __builtin_shufflevector(b0, b1, 0,1,2,3,4,5,6,7);
        acc[0][ni] = __builtin_amdgcn_mfma_scale_f32_16x16x128_f8f6f4(
            af[0][ks], bv, acc[0][ni], 0, 0, 0, 0x7F7F7F7F, 0, 0x7F7F7F7F);
        acc[1][ni] = __builtin_amdgcn_mfma_scale_f32_16x16x128_f8f6f4(
            af[1][ks], bv, acc[1][ni], 0, 0, 0, 0x7F7F7F7F, 0, 0x7F7F7F7F);
      }
    }

    int tcg[4];
    #pragma unroll
    for (int ni = 0; ni < 4; ++ni) tcg[ni] = tgts[c*128 + h*64 + ni*16 + l15];
    #pragma unroll
    for (int mi = 0; mi < 2; ++mi)
      #pragma unroll
      for (int ni = 0; ni < 4; ++ni)
        #pragma unroll
        for (int r = 0; r < 4; ++r) {
          float v = acc[mi][ni][r];
          float e = __builtin_amdgcn_exp2f(fmaf(v, C1, C0));
          bool mt = (tcg[ni] == trow[mi][r]);
          se[mi][r] += e; if (mt) ms[mi][r] += v;
          if (lc) { ce[h][ni] += e; if (mt) cm[h][ni] += v; }
        }

    if (h == 1 && lc) {        // tile complete: quad-reduce -> cred
      #pragma unroll
      for (int g = 0; g < 2; ++g)
        #pragma unroll
        for (int ni = 0; ni < 4; ++ni) {
          float e = ce[g][ni], m = cm[g][ni];
          e += __shfl_xor(e, 16, 64); e += __shfl_xor(e, 32, 64);
          m += __shfl_xor(m, 16, 64); m += __shfl_xor(m, 32, 64);
          if (quad == 0) {
            cred[0][wave][g*64 + ni*16 + l15] = e;
            cred[1][wave][g*64 + ni*16 + l15] = m;
          }
        }
      asm volatile("s_waitcnt lgkmcnt(0)" ::: "memory");  // cred in LDS pre-barrier
    }
  }

  // ---- final tile (c=7) col side; q==3 (t=32) has none ----
  if (q != 3) {
    __builtin_amdgcn_s_barrier();
    const int tf = t0 + 8;
    const int Jf = (I + tf) & 63;
    const int col = tid & 127, arr = tid >> 7;
    float v = cred[arr][0][col] + cred[arr][1][col]
            + cred[arr][2][col] + cred[arr][3][col];
    (arr ? pmask : psum)[(size_t)(3 + tf) * N + Jf * 128 + col] = v;
  }

  // ---- row-side partials -> slot q ----
  #pragma unroll
  for (int mi = 0; mi < 2; ++mi)
    #pragma unroll
    for (int r = 0; r < 4; ++r) {
      float sv = se[mi][r], mv = ms[mi][r];
      #pragma unroll
      for (int off = 1; off < 16; off <<= 1) {
        sv += __shfl_xor(sv, off, 64);
        mv += __shfl_xor(mv, off, 64);
      }
      if (l15 == 0) {
        int row = rowbase + wave*32 + mi*16 + quad*4 + r;
        psum [(size_t)q * N + row] = sv;
        pmask[(size_t)q * N + row] = mv;
      }
    }
}

// finalize: 32 blocks x 256 rows; per-block histogram, per-row term,
// wave reduce, one atomicAdd per block into pre-zeroed out.
// Diagonal handled analytically: s += exp(0)=1 (reference sim_ii=1/T);
// mask-side m excludes the diagonal exactly (matches mask - eye).
__global__ __launch_bounds__(256) void kfinal(
    const float* __restrict__ psum, const float* __restrict__ pmask,
    const int* __restrict__ tgt, float* __restrict__ out, int N, int nslot) {
  __shared__ int h[128];
  __shared__ float wsum[4];
  const int tid = threadIdx.x;
  if (tid < 128) h[tid] = 0;
  __syncthreads();
  for (int i = tid; i < N; i += 256) atomicAdd(&h[tgt[i] & 127], 1);
  __syncthreads();

  const int i = blockIdx.x * 256 + tid;
  float s = 1.f, m = 0.f;           // s starts at the diagonal term
  #pragma unroll 7
  for (int sp = 0; sp < nslot; ++sp) {
    s += psum[(size_t)sp * N + i];
    m += pmask[(size_t)sp * N + i];
  }
  const float invT = 1.0f / TEMP;
  float cnt = (float)(h[tgt[i] & 127] - 1);
  float term = m * invT / cnt - (logf(s) + invT);
  #pragma unroll
  for (int off = 1; off < 64; off <<= 1) term += __shfl_xor(term, off, 64);
  if ((tid & 63) == 0) wsum[tid >> 6] = term;
  __syncthreads();
  if (tid == 0)
    atomicAdd(out, -(wsum[0] + wsum[1] + wsum[2] + wsum[3]) / (float)N);
}

extern "C" void kernel_launch(void* const* d_in, const int* in_sizes, int n_in,
                              void* d_out, int out_size, void* d_ws, size_t ws_size,
                              hipStream_t stream) {
  const float* X  = (const float*)d_in[0];
  const int* tgt  = (const int*)d_in[1];
  float* out      = (float*)d_out;
  const int N = in_sizes[1];
  const int D = in_sizes[0] / N;

  char* w = (char*)d_ws;
  unsigned char* Fq = (unsigned char*)w;
  size_t off = (size_t)N * D;                           // fp8: 1 B/elem (4 MB)
  float* psum  = (float*)(w + off);
  size_t psz = (size_t)NSLOT * N * sizeof(float);       // 1.15 MB
  off += psz;
  float* pmask = (float*)(w + off);                     // total ws ~6.5 MB

  knorm<<<N / 4, 256, 0, stream>>>(X, Fq, out, D);
  kmain<<<256, 256, 0, stream>>>(Fq, tgt, psum, pmask, N, D);
  kfinal<<<N / 256, 256, 0, stream>>>(psum, pmask, tgt, out, N, NSLOT);
}